// Round 1
// baseline (428.150 us; speedup 1.0000x reference)
//
#include <hip/hip_runtime.h>
#include <hip/hip_bf16.h>
#include <stdint.h>

// Problem: B=8, S=2048, H=1024
#define BB 8
#define SS 2048
#define HH 1024

typedef __bf16 bf16_t;
typedef bf16_t bf16x8 __attribute__((ext_vector_type(8)));
typedef float f32x4 __attribute__((ext_vector_type(4)));
typedef unsigned short u16x8 __attribute__((ext_vector_type(8)));

__device__ __forceinline__ unsigned short f2bf(float f) {
    unsigned int u = __float_as_uint(f);
    u += 0x7fffu + ((u >> 16) & 1u);   // RNE
    return (unsigned short)(u >> 16);
}

// ---------------------------------------------------------------------------
// Cast fp32 -> bf16, vectorized x4 (for W)
// ---------------------------------------------------------------------------
__global__ __launch_bounds__(256) void cast_f32_bf16(
    const float* __restrict__ in, unsigned short* __restrict__ out, int n4)
{
    int i = blockIdx.x * blockDim.x + threadIdx.x;
    int stride = gridDim.x * blockDim.x;
    for (; i < n4; i += stride) {
        float4 v = reinterpret_cast<const float4*>(in)[i];
        ushort4 o;
        o.x = f2bf(v.x); o.y = f2bf(v.y); o.z = f2bf(v.z); o.w = f2bf(v.w);
        reinterpret_cast<ushort4*>(out)[i] = o;
    }
}

// ---------------------------------------------------------------------------
// Fused: lstm fp32 [B][S][H] -> lstm_bf16 [B][S][H]  and  lstmT_bf16 [B][H][S]
// 32x32 tiles, block (32,8)
// ---------------------------------------------------------------------------
__global__ __launch_bounds__(256) void transpose_cast(
    const float* __restrict__ in,
    unsigned short* __restrict__ outN,
    unsigned short* __restrict__ outT)
{
    __shared__ float tile[32][33];
    const int tx = threadIdx.x, ty = threadIdx.y;
    const int h0 = blockIdx.x * 32, s0 = blockIdx.y * 32, b = blockIdx.z;
    const float* src = in + ((size_t)b * SS + s0) * HH + h0;
    unsigned short* dN = outN + ((size_t)b * SS + s0) * HH + h0;
    unsigned short* dT = outT + ((size_t)b * HH + h0) * SS + s0;
#pragma unroll
    for (int i = 0; i < 4; i++) {
        float v = src[(size_t)(ty + i * 8) * HH + tx];
        tile[ty + i * 8][tx] = v;
        dN[(size_t)(ty + i * 8) * HH + tx] = f2bf(v);
    }
    __syncthreads();
#pragma unroll
    for (int i = 0; i < 4; i++) {
        dT[(size_t)(ty + i * 8) * SS + tx] = f2bf(tile[tx][ty + i * 8]);
    }
}

// ---------------------------------------------------------------------------
// Row softmax over score fp32 [16384][2048], written in-place as bf16 rows
// at element stride 4096 (same byte offset per row -> no cross-block races).
// One 256-thread block per row; 8 values per thread.
// ---------------------------------------------------------------------------
__global__ __launch_bounds__(256) void softmax_rows(float* __restrict__ score)
{
    const size_t row = blockIdx.x;
    float* srow = score + row * 2048;
    const int t = threadIdx.x;
    const int wave = t >> 6, lane = t & 63;

    float4 v0 = reinterpret_cast<float4*>(srow)[t * 2];
    float4 v1 = reinterpret_cast<float4*>(srow)[t * 2 + 1];
    float x[8] = {v0.x, v0.y, v0.z, v0.w, v1.x, v1.y, v1.z, v1.w};

    float m = x[0];
#pragma unroll
    for (int i = 1; i < 8; i++) m = fmaxf(m, x[i]);
#pragma unroll
    for (int off = 32; off; off >>= 1) m = fmaxf(m, __shfl_xor(m, off));

    __shared__ float red[4];
    if (!lane) red[wave] = m;
    __syncthreads();
    m = fmaxf(fmaxf(red[0], red[1]), fmaxf(red[2], red[3]));

    float e[8];
    float s = 0.0f;
#pragma unroll
    for (int i = 0; i < 8; i++) { e[i] = __expf(x[i] - m); s += e[i]; }
#pragma unroll
    for (int off = 32; off; off >>= 1) s += __shfl_xor(s, off);
    __syncthreads();
    if (!lane) red[wave] = s;
    __syncthreads();
    s = red[0] + red[1] + red[2] + red[3];
    const float inv = 1.0f / s;

    unsigned short* drow = reinterpret_cast<unsigned short*>(score) + row * 4096 + (size_t)t * 8;
    u16x8 o;
#pragma unroll
    for (int i = 0; i < 8; i++) o[i] = f2bf(e[i] * inv);
    *reinterpret_cast<u16x8*>(drow) = o;
}

// ---------------------------------------------------------------------------
// NT GEMM (m97 structure): C[M,N] = A[M,K] * B[N,K]^T (+bias), bf16 in, f32 acc
// 128x128 tile, BK=32, 256 threads (4 waves, 2x2), 16x16x32 MFMA,
// global_load_lds width-16 staging.
// All of M,N divisible by 128; K divisible by 32. lda/ldb rows 16B-aligned.
// ---------------------------------------------------------------------------
#define GLL16(gp, lp)                                                        \
    __builtin_amdgcn_global_load_lds(                                        \
        (const __attribute__((address_space(1))) unsigned int*)(gp),         \
        (__attribute__((address_space(3))) unsigned int*)(lp), 16, 0, 0)

template <int OUT_BF16, int HAS_BIAS>
__global__ __launch_bounds__(256) void gemm_nt(
    const unsigned short* __restrict__ A, long long aBatch, int lda,
    const unsigned short* __restrict__ Bmat, long long bBatch, int ldb,
    void* __restrict__ Cp, long long cBatch, int ldc,
    const float* __restrict__ bias, int K)
{
    __shared__ unsigned short As[128 * 32];
    __shared__ unsigned short Bs[128 * 32];

    const int tid = threadIdx.x;
    const int wave = tid >> 6, lane = tid & 63;
    const int wr = wave >> 1, wc = wave & 1;
    const int fr = lane & 15;         // fragment row (A) / col (B) / col (C)
    const int fk = (lane >> 4) * 8;   // fragment k offset

    // staging: each wave stages 32 rows of A and 32 rows of B per K-step,
    // in two 16-row chunks (64 lanes x 16B = 16 rows x 64B)
    const unsigned short* Ab = A + (size_t)blockIdx.z * aBatch
        + ((size_t)blockIdx.y * 128 + wave * 32 + (lane >> 2)) * lda + (lane & 3) * 8;
    const unsigned short* Bb = Bmat + (size_t)blockIdx.z * bBatch
        + ((size_t)blockIdx.x * 128 + wave * 32 + (lane >> 2)) * ldb + (lane & 3) * 8;
    unsigned short* lA0 = As + (wave * 32) * 32;
    unsigned short* lA1 = As + (wave * 32 + 16) * 32;
    unsigned short* lB0 = Bs + (wave * 32) * 32;
    unsigned short* lB1 = Bs + (wave * 32 + 16) * 32;
    const size_t a16 = (size_t)16 * lda, b16 = (size_t)16 * ldb;

    f32x4 acc[4][4];
    const f32x4 zero = {0.0f, 0.0f, 0.0f, 0.0f};
#pragma unroll
    for (int m = 0; m < 4; m++)
#pragma unroll
        for (int n = 0; n < 4; n++) acc[m][n] = zero;

    for (int k0 = 0; k0 < K; k0 += 32) {
        GLL16(Ab + k0, lA0);
        GLL16(Ab + k0 + a16, lA1);
        GLL16(Bb + k0, lB0);
        GLL16(Bb + k0 + b16, lB1);
        __syncthreads();   // compiler drains vmcnt before s_barrier

        bf16x8 aF[4], bF[4];
#pragma unroll
        for (int m = 0; m < 4; m++)
            aF[m] = *reinterpret_cast<const bf16x8*>(As + (wr * 64 + m * 16 + fr) * 32 + fk);
#pragma unroll
        for (int n = 0; n < 4; n++)
            bF[n] = *reinterpret_cast<const bf16x8*>(Bs + (wc * 64 + n * 16 + fr) * 32 + fk);
#pragma unroll
        for (int m = 0; m < 4; m++)
#pragma unroll
            for (int n = 0; n < 4; n++)
                acc[m][n] = __builtin_amdgcn_mfma_f32_16x16x32_bf16(aF[m], bF[n], acc[m][n], 0, 0, 0);
        __syncthreads();
    }

    // Epilogue. C/D frag: col = lane&15, row = (lane>>4)*4 + j  [m89-verified]
    const int rBase = blockIdx.y * 128 + wr * 64 + (lane >> 4) * 4;
    const int cBase = blockIdx.x * 128 + wc * 64 + fr;
    if (OUT_BF16) {
        unsigned short* C = (unsigned short*)Cp + (size_t)blockIdx.z * cBatch;
#pragma unroll
        for (int n = 0; n < 4; n++) {
            const int col = cBase + n * 16;
            const float bv = HAS_BIAS ? bias[col] : 0.0f;
#pragma unroll
            for (int m = 0; m < 4; m++) {
                const int row = rBase + m * 16;
#pragma unroll
                for (int j = 0; j < 4; j++)
                    C[(size_t)(row + j) * ldc + col] = f2bf(acc[m][n][j] + bv);
            }
        }
    } else {
        float* C = (float*)Cp + (size_t)blockIdx.z * cBatch;
#pragma unroll
        for (int n = 0; n < 4; n++) {
            const int col = cBase + n * 16;
#pragma unroll
            for (int m = 0; m < 4; m++) {
                const int row = rBase + m * 16;
#pragma unroll
                for (int j = 0; j < 4; j++)
                    C[(size_t)(row + j) * ldc + col] = acc[m][n][j];
            }
        }
    }
}

// ---------------------------------------------------------------------------
// Launch
// ---------------------------------------------------------------------------
extern "C" void kernel_launch(void* const* d_in, const int* in_sizes, int n_in,
                              void* d_out, int out_size, void* d_ws, size_t ws_size,
                              hipStream_t stream)
{
    const float* lstm = (const float*)d_in[0];   // [B,S,H] f32
    const float* W    = (const float*)d_in[1];   // [H,H]   f32
    const float* bias = (const float*)d_in[2];   // [H]     f32
    float* out = (float*)d_out;                  // [B,S,H] f32

    // workspace layout (bytes):
    //   lstm_bf16 [B*S, H]      32 MB
    //   out_bf16  [B*S, H]      32 MB
    //   lstmT     [B, H, S]     32 MB
    //   W_bf16    [H, H]         2 MB
    //   score     [B, S, S] f32 128 MB  (softmax rewrites rows in-place as
    //                                    bf16 at element stride 4096)
    unsigned short* lstm_bf = (unsigned short*)d_ws;
    unsigned short* out_bf  = lstm_bf + (size_t)BB * SS * HH;
    unsigned short* lstmT   = out_bf + (size_t)BB * SS * HH;
    unsigned short* W_bf    = lstmT + (size_t)BB * HH * SS;
    float* score            = (float*)(W_bf + (size_t)HH * HH);

    // 1) lstm -> bf16 (row-major + transposed)
    transpose_cast<<<dim3(HH / 32, SS / 32, BB), dim3(32, 8), 0, stream>>>(
        lstm, lstm_bf, lstmT);

    // 2) W -> bf16
    cast_f32_bf16<<<dim3(512), dim3(256), 0, stream>>>(W, W_bf, HH * HH / 4);

    // 3) out = lstm @ W^T + b   (M=B*S=16384, N=H, K=H), bf16 output
    gemm_nt<1, 1><<<dim3(HH / 128, BB * SS / 128, 1), dim3(256), 0, stream>>>(
        lstm_bf, 0, HH, W_bf, 0, HH, out_bf, 0, HH, bias, HH);

    // 4) score[b] = out[b] @ out[b]^T   (M=N=S, K=H), fp32 output
    gemm_nt<0, 0><<<dim3(SS / 128, SS / 128, BB), dim3(256), 0, stream>>>(
        out_bf, (long long)SS * HH, HH,
        out_bf, (long long)SS * HH, HH,
        score, (long long)SS * SS, SS, nullptr, HH);

    // 5) softmax rows, in-place fp32 -> bf16 (stride 4096 elements)
    softmax_rows<<<dim3(BB * SS), dim3(256), 0, stream>>>(score);

    // 6) context[b] = attn[b] @ lstm[b]  via  attn[b] @ (lstmT[b])^T
    //    (M=S, N=H, K=S), fp32 output to d_out
    gemm_nt<0, 0><<<dim3(HH / 128, SS / 128, BB), dim3(256), 0, stream>>>(
        (const unsigned short*)score, (long long)SS * 4096, 4096,
        lstmT, (long long)HH * SS, SS,
        out, (long long)SS * HH, HH, nullptr, SS);
}

// Round 3
// 349.506 us; speedup vs baseline: 1.2250x; 1.2250x over previous
//
#include <hip/hip_runtime.h>
#include <hip/hip_bf16.h>
#include <stdint.h>

// Problem: B=8, S=2048, H=1024
#define BB 8
#define SS 2048
#define HH 1024

typedef __bf16 bf16_t;
typedef bf16_t bf16x8 __attribute__((ext_vector_type(8)));
typedef float f32x4 __attribute__((ext_vector_type(4)));
typedef unsigned short u16x8 __attribute__((ext_vector_type(8)));

__device__ __forceinline__ unsigned short f2bf(float f) {
    unsigned int u = __float_as_uint(f);
    u += 0x7fffu + ((u >> 16) & 1u);   // RNE
    return (unsigned short)(u >> 16);
}
__device__ __forceinline__ float bf2f(unsigned short h) {
    return __uint_as_float((unsigned int)h << 16);
}

// ---------------------------------------------------------------------------
// Cast fp32 -> bf16, vectorized x4 (for W)
// ---------------------------------------------------------------------------
__global__ __launch_bounds__(256) void cast_f32_bf16(
    const float* __restrict__ in, unsigned short* __restrict__ out, int n4)
{
    int i = blockIdx.x * blockDim.x + threadIdx.x;
    int stride = gridDim.x * blockDim.x;
    for (; i < n4; i += stride) {
        float4 v = reinterpret_cast<const float4*>(in)[i];
        ushort4 o;
        o.x = f2bf(v.x); o.y = f2bf(v.y); o.z = f2bf(v.z); o.w = f2bf(v.w);
        reinterpret_cast<ushort4*>(out)[i] = o;
    }
}

// ---------------------------------------------------------------------------
// Fused: lstm fp32 [B][S][H] -> lstm_bf16 [B][S][H]  and  lstmT_bf16 [B][H][S]
// ---------------------------------------------------------------------------
__global__ __launch_bounds__(256) void transpose_cast(
    const float* __restrict__ in,
    unsigned short* __restrict__ outN,
    unsigned short* __restrict__ outT)
{
    __shared__ float tile[32][33];
    const int tx = threadIdx.x, ty = threadIdx.y;
    const int h0 = blockIdx.x * 32, s0 = blockIdx.y * 32, b = blockIdx.z;
    const float* src = in + ((size_t)b * SS + s0) * HH + h0;
    unsigned short* dN = outN + ((size_t)b * SS + s0) * HH + h0;
    unsigned short* dT = outT + ((size_t)b * HH + h0) * SS + s0;
#pragma unroll
    for (int i = 0; i < 4; i++) {
        float v = src[(size_t)(ty + i * 8) * HH + tx];
        tile[ty + i * 8][tx] = v;
        dN[(size_t)(ty + i * 8) * HH + tx] = f2bf(v);
    }
    __syncthreads();
#pragma unroll
    for (int i = 0; i < 4; i++) {
        dT[(size_t)(ty + i * 8) * SS + tx] = f2bf(tile[tx][ty + i * 8]);
    }
}

// ---------------------------------------------------------------------------
// Row softmax over bf16 logits [16384][2048], in-place bf16 -> bf16.
// One 256-thread block per row; 8 values per thread.
// ---------------------------------------------------------------------------
__global__ __launch_bounds__(256) void softmax_rows_bf16(unsigned short* __restrict__ score)
{
    const size_t row = blockIdx.x;
    unsigned short* srow = score + row * 2048;
    const int t = threadIdx.x;
    const int wave = t >> 6, lane = t & 63;

    u16x8 v = *reinterpret_cast<u16x8*>(srow + (size_t)t * 8);
    float x[8];
#pragma unroll
    for (int i = 0; i < 8; i++) x[i] = bf2f(v[i]);

    float m = x[0];
#pragma unroll
    for (int i = 1; i < 8; i++) m = fmaxf(m, x[i]);
#pragma unroll
    for (int off = 32; off; off >>= 1) m = fmaxf(m, __shfl_xor(m, off));

    __shared__ float red[4];
    if (!lane) red[wave] = m;
    __syncthreads();
    m = fmaxf(fmaxf(red[0], red[1]), fmaxf(red[2], red[3]));

    float e[8];
    float s = 0.0f;
#pragma unroll
    for (int i = 0; i < 8; i++) { e[i] = __expf(x[i] - m); s += e[i]; }
#pragma unroll
    for (int off = 32; off; off >>= 1) s += __shfl_xor(s, off);
    __syncthreads();
    if (!lane) red[wave] = s;
    __syncthreads();
    s = red[0] + red[1] + red[2] + red[3];
    const float inv = 1.0f / s;

    u16x8 o;
#pragma unroll
    for (int i = 0; i < 8; i++) o[i] = f2bf(e[i] * inv);
    *reinterpret_cast<u16x8*>(srow + (size_t)t * 8) = o;
}

// ---------------------------------------------------------------------------
// 256x256 deep-pipelined NT GEMM: C[M,N] = A[M,K]*B[N,K]^T (+bias)
// bf16 in, f32 acc. BK=32, 512 threads = 8 waves (2 Mx4 N), per-wave 128x64.
// 3 LDS buffers (96 KB), lookahead-2 staging via global_load_lds w16,
// counted vmcnt(4) (never drains in-loop), LDS chunk-XOR swizzle (T2),
// setprio around MFMA clusters (T5), 2 phases per K-tile (T3-style).
// Requires: M%256==0, N%256==0, K%32==0, K/32>=2, gridDim.x%8==0.
// ---------------------------------------------------------------------------
#define GLL16(gp, lp)                                                        \
    __builtin_amdgcn_global_load_lds(                                        \
        (const __attribute__((address_space(1))) unsigned int*)(gp),         \
        (__attribute__((address_space(3))) unsigned int*)(lp), 16, 0, 0)

template <int OUT_BF16, int HAS_BIAS>
__global__ __launch_bounds__(512, 2) void gemm_nt_256(
    const unsigned short* __restrict__ A, long long aBatch, int lda,
    const unsigned short* __restrict__ Bm, long long bBatch, int ldb,
    void* __restrict__ Cp, long long cBatch, int ldc,
    const float* __restrict__ bias, int K, int GXT)
{
    // [3 buffers][A 8192 | B 8192] ushorts = 96 KB
    __shared__ unsigned short lds[3 * 16384];

    const int tid = threadIdx.x;
    const int wave = tid >> 6, lane = tid & 63;
    const int wr = wave >> 2, wc = wave & 3;     // 2 x 4 wave grid
    const int fr = lane & 15, fc = lane >> 4;

    // XCD-aware bijective swizzle (gridDim.x % 8 == 0)
    const int q = gridDim.x >> 3;
    const int x = blockIdx.x;
    const int wgid = (x & 7) * q + (x >> 3);
    const int bx = wgid % GXT, by = wgid / GXT;

    const unsigned short* Ap = A + (size_t)blockIdx.z * aBatch + (size_t)by * 256 * lda;
    const unsigned short* Bp = Bm + (size_t)blockIdx.z * bBatch + (size_t)bx * 256 * ldb;

    // ---- staging addresses (source pre-swizzled; LDS dest linear) ----
    const int sr = tid >> 2;          // dest row (sweep0), sweep1 = +128
    const int sc = tid & 3;           // dest 16B chunk
    const int r0 = sr, r1 = sr + 128;
    const unsigned short* sA0 = Ap + (size_t)r0 * lda + ((sc ^ ((r0 >> 1) & 3)) << 3);
    const unsigned short* sA1 = Ap + (size_t)r1 * lda + ((sc ^ ((r1 >> 1) & 3)) << 3);
    const unsigned short* sB0 = Bp + (size_t)r0 * ldb + ((sc ^ ((r0 >> 1) & 3)) << 3);
    const unsigned short* sB1 = Bp + (size_t)r1 * ldb + ((sc ^ ((r1 >> 1) & 3)) << 3);
    const int dA0 = wave * 512;                 // wave-uniform LDS dest (ushort units)
    const int dA1 = 4096 + wave * 512;

    // ---- fragment read offsets (swizzled ds_read) ----
    // row R -> ushort off = R*32 + ((fc ^ ((R>>1)&3))<<3); xor term == (fr>>1)&3 for all frags
    const int kch = ((fc ^ ((fr >> 1) & 3)) << 3);
    int offA[8], offB[4];
#pragma unroll
    for (int m = 0; m < 8; m++) offA[m] = (wr * 128 + m * 16 + fr) * 32 + kch;
#pragma unroll
    for (int n = 0; n < 4; n++) offB[n] = (wc * 64 + n * 16 + fr) * 32 + kch;

    f32x4 acc[8][4];
    const f32x4 zero = {0.0f, 0.0f, 0.0f, 0.0f};
#pragma unroll
    for (int m = 0; m < 8; m++)
#pragma unroll
        for (int n = 0; n < 4; n++) acc[m][n] = zero;

    const int NT = K >> 5;   // K-tiles of 32

    // ---- prologue: stage tiles 0,1 (A then B each: 4 gll/thread/tile) ----
    {
        unsigned short* b0 = lds;           // buffer 0
        unsigned short* b1 = lds + 16384;   // buffer 1
        GLL16(sA0, b0 + dA0); GLL16(sA1, b0 + dA1);
        GLL16(sB0, b0 + 8192 + dA0); GLL16(sB1, b0 + 8192 + dA1);
        GLL16(sA0 + 32, b1 + dA0); GLL16(sA1 + 32, b1 + dA1);
        GLL16(sB0 + 32, b1 + 8192 + dA0); GLL16(sB1 + 32, b1 + 8192 + dA1);
    }
    asm volatile("s_waitcnt vmcnt(4)" ::: "memory");   // tile 0 landed
    __builtin_amdgcn_sched_barrier(0);
    __builtin_amdgcn_s_barrier();

    for (int t = 0; t < NT; ++t) {
        const int cur = t % 3;
        const int nb = (t + 2) % 3;
        const int sk = (t + 2 < NT ? t + 2 : NT - 1) << 5;   // clamped (keeps vmcnt uniform)
        const unsigned short* tA = lds + cur * 16384;
        const unsigned short* tB = tA + 8192;
        unsigned short* nA = lds + nb * 16384;
        unsigned short* nB = nA + 8192;

        // ---- phase 0: read aF[0..3] + bF[0..3]; stage A(t+2); MFMA mh0 ----
        bf16x8 a0[4], b0[4];
#pragma unroll
        for (int m = 0; m < 4; m++)
            a0[m] = *reinterpret_cast<const bf16x8*>(tA + offA[m]);
#pragma unroll
        for (int n = 0; n < 4; n++)
            b0[n] = *reinterpret_cast<const bf16x8*>(tB + offB[n]);
        GLL16(sA0 + sk, nA + dA0);
        GLL16(sA1 + sk, nA + dA1);
        __builtin_amdgcn_s_barrier();
        __builtin_amdgcn_s_setprio(1);
#pragma unroll
        for (int m = 0; m < 4; m++)
#pragma unroll
            for (int n = 0; n < 4; n++)
                acc[m][n] = __builtin_amdgcn_mfma_f32_16x16x32_bf16(a0[m], b0[n], acc[m][n], 0, 0, 0);
        __builtin_amdgcn_s_setprio(0);
        __builtin_amdgcn_s_barrier();

        // ---- phase 1: read aF[4..7]; stage B(t+2); MFMA mh1; counted vmcnt ----
        bf16x8 a1[4];
#pragma unroll
        for (int m = 0; m < 4; m++)
            a1[m] = *reinterpret_cast<const bf16x8*>(tA + offA[4 + m]);
        GLL16(sB0 + sk, nB + dA0);
        GLL16(sB1 + sk, nB + dA1);
        __builtin_amdgcn_s_barrier();
        __builtin_amdgcn_s_setprio(1);
#pragma unroll
        for (int m = 0; m < 4; m++)
#pragma unroll
            for (int n = 0; n < 4; n++)
                acc[4 + m][n] = __builtin_amdgcn_mfma_f32_16x16x32_bf16(a1[m], b0[n], acc[4 + m][n], 0, 0, 0);
        __builtin_amdgcn_s_setprio(0);
        asm volatile("s_waitcnt vmcnt(4)" ::: "memory");   // tile t+1 landed; t+2 in flight
        __builtin_amdgcn_sched_barrier(0);
        __builtin_amdgcn_s_barrier();
    }
    asm volatile("s_waitcnt vmcnt(0)" ::: "memory");   // drain trailing stages before endpgm
    __builtin_amdgcn_sched_barrier(0);

    // ---- epilogue: C/D frag col = lane&15, row = (lane>>4)*4 + j ----
    const int rBase = by * 256 + wr * 128 + fc * 4;
    const int cBase = bx * 256 + wc * 64 + fr;
    if (OUT_BF16) {
        unsigned short* C = (unsigned short*)Cp + (size_t)blockIdx.z * cBatch;
#pragma unroll
        for (int n = 0; n < 4; n++) {
            const int col = cBase + n * 16;
            const float bv = HAS_BIAS ? bias[col] : 0.0f;
#pragma unroll
            for (int m = 0; m < 8; m++) {
                const int row = rBase + m * 16;
#pragma unroll
                for (int j = 0; j < 4; j++)
                    C[(size_t)(row + j) * ldc + col] = f2bf(acc[m][n][j] + bv);
            }
        }
    } else {
        float* C = (float*)Cp + (size_t)blockIdx.z * cBatch;
#pragma unroll
        for (int n = 0; n < 4; n++) {
            const int col = cBase + n * 16;
#pragma unroll
            for (int m = 0; m < 8; m++) {
                const int row = rBase + m * 16;
#pragma unroll
                for (int j = 0; j < 4; j++)
                    C[(size_t)(row + j) * ldc + col] = acc[m][n][j];
            }
        }
    }
}

// ---------------------------------------------------------------------------
// Launch
// ---------------------------------------------------------------------------
extern "C" void kernel_launch(void* const* d_in, const int* in_sizes, int n_in,
                              void* d_out, int out_size, void* d_ws, size_t ws_size,
                              hipStream_t stream)
{
    const float* lstm = (const float*)d_in[0];   // [B,S,H] f32
    const float* W    = (const float*)d_in[1];   // [H,H]   f32
    const float* bias = (const float*)d_in[2];   // [H]     f32
    float* out = (float*)d_out;                  // [B,S,H] f32

    // workspace (ushorts): lstm_bf 16M | out_bf 16M | lstmT 16M | W_bf 1M | score_bf 32M
    unsigned short* lstm_bf = (unsigned short*)d_ws;
    unsigned short* out_bf  = lstm_bf + (size_t)BB * SS * HH;
    unsigned short* lstmT   = out_bf + (size_t)BB * SS * HH;
    unsigned short* W_bf    = lstmT + (size_t)BB * HH * SS;
    unsigned short* score   = W_bf + (size_t)HH * HH;

    // 1) lstm -> bf16 (row-major + transposed)
    transpose_cast<<<dim3(HH / 32, SS / 32, BB), dim3(32, 8), 0, stream>>>(
        lstm, lstm_bf, lstmT);

    // 2) W -> bf16
    cast_f32_bf16<<<dim3(512), dim3(256), 0, stream>>>(W, W_bf, HH * HH / 4);

    // 3) out = lstm @ W^T + b   (M=16384, N=1024, K=1024), bf16 out
    gemm_nt_256<1, 1><<<dim3(256, 1, 1), dim3(512), 0, stream>>>(
        lstm_bf, 0, HH, W_bf, 0, HH, out_bf, 0, HH, bias, HH, HH / 256);

    // 4) score[b] = out[b] @ out[b]^T  (M=N=2048, K=1024), bf16 logits
    gemm_nt_256<1, 0><<<dim3(64, 1, BB), dim3(512), 0, stream>>>(
        out_bf, (long long)SS * HH, HH,
        out_bf, (long long)SS * HH, HH,
        score, (long long)SS * SS, SS, nullptr, HH, SS / 256);

    // 5) softmax rows, in-place bf16
    softmax_rows_bf16<<<dim3(BB * SS), dim3(256), 0, stream>>>(score);

    // 6) context[b] = attn[b] @ lstm[b] = attn[b] @ (lstmT[b])^T
    //    (M=2048, N=1024, K=2048), fp32 out
    gemm_nt_256<0, 0><<<dim3(32, 1, BB), dim3(512), 0, stream>>>(
        score, (long long)SS * SS, SS,
        lstmT, (long long)HH * SS, SS,
        out, (long long)SS * HH, HH, nullptr, SS, HH / 256);
}

// Round 12
// 346.937 us; speedup vs baseline: 1.2341x; 1.0074x over previous
//
#include <hip/hip_runtime.h>
#include <hip/hip_bf16.h>
#include <stdint.h>

// Problem: B=8, S=2048, H=1024
#define BB 8
#define SS 2048
#define HH 1024

typedef __bf16 bf16_t;
typedef bf16_t bf16x8 __attribute__((ext_vector_type(8)));
typedef float f32x4 __attribute__((ext_vector_type(4)));
typedef unsigned short u16x8 __attribute__((ext_vector_type(8)));

__device__ __forceinline__ unsigned short f2bf(float f) {
    unsigned int u = __float_as_uint(f);
    u += 0x7fffu + ((u >> 16) & 1u);   // RNE
    return (unsigned short)(u >> 16);
}
__device__ __forceinline__ float bf2f(unsigned short h) {
    return __uint_as_float((unsigned int)h << 16);
}

// ---------------------------------------------------------------------------
// Cast fp32 -> bf16, vectorized x4 (for W)
// ---------------------------------------------------------------------------
__global__ __launch_bounds__(256) void cast_f32_bf16(
    const float* __restrict__ in, unsigned short* __restrict__ out, int n4)
{
    int i = blockIdx.x * blockDim.x + threadIdx.x;
    int stride = gridDim.x * blockDim.x;
    for (; i < n4; i += stride) {
        float4 v = reinterpret_cast<const float4*>(in)[i];
        ushort4 o;
        o.x = f2bf(v.x); o.y = f2bf(v.y); o.z = f2bf(v.z); o.w = f2bf(v.w);
        reinterpret_cast<ushort4*>(out)[i] = o;
    }
}

// ---------------------------------------------------------------------------
// Fused: lstm fp32 [B][S][H] -> lstm_bf16 [B][S][H]  and  lstmT_bf16 [B][H][S]
// 32x32 tile, 256 threads, float4 loads + ushort4 stores (vectorized R11).
// Thread t: row = t>>3 (0..31), c4 = t&7 (4-col group).
// ---------------------------------------------------------------------------
__global__ __launch_bounds__(256) void transpose_cast(
    const float* __restrict__ in,
    unsigned short* __restrict__ outN,
    unsigned short* __restrict__ outT)
{
    __shared__ float tile[32][33];
    const int t = threadIdx.x;
    const int row = t >> 3;        // 0..31
    const int c4  = t & 7;         // 0..7
    const int h0 = blockIdx.x * 32, s0 = blockIdx.y * 32, b = blockIdx.z;

    const float* src = in + ((size_t)b * SS + s0 + row) * HH + h0 + c4 * 4;
    const float4 v = *reinterpret_cast<const float4*>(src);
    ushort4 o;
    o.x = f2bf(v.x); o.y = f2bf(v.y); o.z = f2bf(v.z); o.w = f2bf(v.w);
    *reinterpret_cast<ushort4*>(outN + ((size_t)b * SS + s0 + row) * HH + h0 + c4 * 4) = o;
    tile[row][c4 * 4 + 0] = v.x;
    tile[row][c4 * 4 + 1] = v.y;
    tile[row][c4 * 4 + 2] = v.z;
    tile[row][c4 * 4 + 3] = v.w;
    __syncthreads();
    // outT[b][h0+row][s0+4*c4+j] = in[b][s0+4*c4+j][h0+row] = tile[4*c4+j][row]
    ushort4 p;
    p.x = f2bf(tile[c4 * 4 + 0][row]);
    p.y = f2bf(tile[c4 * 4 + 1][row]);
    p.z = f2bf(tile[c4 * 4 + 2][row]);
    p.w = f2bf(tile[c4 * 4 + 3][row]);
    *reinterpret_cast<ushort4*>(outT + ((size_t)b * HH + h0 + row) * SS + s0 + c4 * 4) = p;
}

// ---------------------------------------------------------------------------
// Row softmax over bf16 logits [16384][2048], in-place bf16 -> bf16.
// ---------------------------------------------------------------------------
__global__ __launch_bounds__(256) void softmax_rows_bf16(unsigned short* __restrict__ score)
{
    const size_t row = blockIdx.x;
    unsigned short* srow = score + row * 2048;
    const int t = threadIdx.x;
    const int wave = t >> 6, lane = t & 63;

    u16x8 v = *reinterpret_cast<u16x8*>(srow + (size_t)t * 8);
    float x[8];
#pragma unroll
    for (int i = 0; i < 8; i++) x[i] = bf2f(v[i]);

    float m = x[0];
#pragma unroll
    for (int i = 1; i < 8; i++) m = fmaxf(m, x[i]);
#pragma unroll
    for (int off = 32; off; off >>= 1) m = fmaxf(m, __shfl_xor(m, off));

    __shared__ float red[4];
    if (!lane) red[wave] = m;
    __syncthreads();
    m = fmaxf(fmaxf(red[0], red[1]), fmaxf(red[2], red[3]));

    float e[8];
    float s = 0.0f;
#pragma unroll
    for (int i = 0; i < 8; i++) { e[i] = __expf(x[i] - m); s += e[i]; }
#pragma unroll
    for (int off = 32; off; off >>= 1) s += __shfl_xor(s, off);
    __syncthreads();
    if (!lane) red[wave] = s;
    __syncthreads();
    s = red[0] + red[1] + red[2] + red[3];
    const float inv = 1.0f / s;

    u16x8 o;
#pragma unroll
    for (int i = 0; i < 8; i++) o[i] = f2bf(e[i] * inv);
    *reinterpret_cast<u16x8*>(srow + (size_t)t * 8) = o;
}

// ---------------------------------------------------------------------------
// 256x256 deep-pipelined NT GEMM: C[M,N] = A[M,K]*B[N,K]^T (+bias)
// bf16 in, f32 acc. BK=32, 512 threads = 8 waves (2 Mx4 N), per-wave 128x64.
// 4 LDS buffers (128 KB ring), LOOKAHEAD-3 staging via global_load_lds w16,
// counted vmcnt(8) (never drains in-loop), LDS chunk-XOR swizzle (T2),
// setprio around MFMA clusters (T5), 2 phases per K-tile (T3-style).
// Requires: M%256==0, N%256==0, K%32==0, K/32>=3, gridDim.x%8==0.
// ---------------------------------------------------------------------------
#define GLL16(gp, lp)                                                        \
    __builtin_amdgcn_global_load_lds(                                        \
        (const __attribute__((address_space(1))) unsigned int*)(gp),         \
        (__attribute__((address_space(3))) unsigned int*)(lp), 16, 0, 0)

template <int OUT_BF16, int HAS_BIAS>
__global__ __launch_bounds__(512, 2) void gemm_nt_256(
    const unsigned short* __restrict__ A, long long aBatch, int lda,
    const unsigned short* __restrict__ Bm, long long bBatch, int ldb,
    void* __restrict__ Cp, long long cBatch, int ldc,
    const float* __restrict__ bias, int K, int GXT)
{
    // [4 buffers][A 8192 | B 8192] ushorts = 128 KB
    __shared__ unsigned short lds[4 * 16384];

    const int tid = threadIdx.x;
    const int wave = tid >> 6, lane = tid & 63;
    const int wr = wave >> 2, wc = wave & 3;     // 2 x 4 wave grid
    const int fr = lane & 15, fc = lane >> 4;

    // XCD-aware bijective swizzle (gridDim.x % 8 == 0)
    const int q = gridDim.x >> 3;
    const int x = blockIdx.x;
    const int wgid = (x & 7) * q + (x >> 3);
    const int bx = wgid % GXT, by = wgid / GXT;

    const unsigned short* Ap = A + (size_t)blockIdx.z * aBatch + (size_t)by * 256 * lda;
    const unsigned short* Bp = Bm + (size_t)blockIdx.z * bBatch + (size_t)bx * 256 * ldb;

    // ---- staging addresses (source pre-swizzled; LDS dest linear) ----
    const int sr = tid >> 2;          // dest row (sweep0), sweep1 = +128
    const int sc = tid & 3;           // dest 16B chunk
    const int r0 = sr, r1 = sr + 128;
    const unsigned short* sA0 = Ap + (size_t)r0 * lda + ((sc ^ ((r0 >> 1) & 3)) << 3);
    const unsigned short* sA1 = Ap + (size_t)r1 * lda + ((sc ^ ((r1 >> 1) & 3)) << 3);
    const unsigned short* sB0 = Bp + (size_t)r0 * ldb + ((sc ^ ((r0 >> 1) & 3)) << 3);
    const unsigned short* sB1 = Bp + (size_t)r1 * ldb + ((sc ^ ((r1 >> 1) & 3)) << 3);
    const int dA0 = wave * 512;                 // wave-uniform LDS dest (ushort units)
    const int dA1 = 4096 + wave * 512;

    // ---- fragment read offsets (swizzled ds_read) ----
    const int kch = ((fc ^ ((fr >> 1) & 3)) << 3);
    int offA[8], offB[4];
#pragma unroll
    for (int m = 0; m < 8; m++) offA[m] = (wr * 128 + m * 16 + fr) * 32 + kch;
#pragma unroll
    for (int n = 0; n < 4; n++) offB[n] = (wc * 64 + n * 16 + fr) * 32 + kch;

    f32x4 acc[8][4];
    const f32x4 zero = {0.0f, 0.0f, 0.0f, 0.0f};
#pragma unroll
    for (int m = 0; m < 8; m++)
#pragma unroll
        for (int n = 0; n < 4; n++) acc[m][n] = zero;

    const int NT = K >> 5;   // K-tiles of 32

    // ---- prologue: stage tiles 0,1,2 into buffers 0,1,2 ----
    {
        unsigned short* b0 = lds;
        unsigned short* b1 = lds + 16384;
        unsigned short* b2 = lds + 32768;
        GLL16(sA0, b0 + dA0); GLL16(sA1, b0 + dA1);
        GLL16(sB0, b0 + 8192 + dA0); GLL16(sB1, b0 + 8192 + dA1);
        GLL16(sA0 + 32, b1 + dA0); GLL16(sA1 + 32, b1 + dA1);
        GLL16(sB0 + 32, b1 + 8192 + dA0); GLL16(sB1 + 32, b1 + 8192 + dA1);
        GLL16(sA0 + 64, b2 + dA0); GLL16(sA1 + 64, b2 + dA1);
        GLL16(sB0 + 64, b2 + 8192 + dA0); GLL16(sB1 + 64, b2 + 8192 + dA1);
    }
    asm volatile("s_waitcnt vmcnt(8)" ::: "memory");   // tile 0 landed; 1,2 in flight
    __builtin_amdgcn_sched_barrier(0);
    __builtin_amdgcn_s_barrier();

    for (int t = 0; t < NT; ++t) {
        const int cur = t & 3;
        const int nb = (t + 3) & 3;
        const int sk = (t + 3 < NT ? t + 3 : NT - 1) << 5;   // clamped (keeps vmcnt uniform)
        const unsigned short* tA = lds + cur * 16384;
        const unsigned short* tB = tA + 8192;
        unsigned short* nA = lds + nb * 16384;
        unsigned short* nB = nA + 8192;

        // ---- phase 0: read aF[0..3] + bF[0..3]; stage A(t+3); MFMA mh0 ----
        bf16x8 a0[4], b0[4];
#pragma unroll
        for (int m = 0; m < 4; m++)
            a0[m] = *reinterpret_cast<const bf16x8*>(tA + offA[m]);
#pragma unroll
        for (int n = 0; n < 4; n++)
            b0[n] = *reinterpret_cast<const bf16x8*>(tB + offB[n]);
        GLL16(sA0 + sk, nA + dA0);
        GLL16(sA1 + sk, nA + dA1);
        __builtin_amdgcn_s_barrier();
        __builtin_amdgcn_s_setprio(1);
#pragma unroll
        for (int m = 0; m < 4; m++)
#pragma unroll
            for (int n = 0; n < 4; n++)
                acc[m][n] = __builtin_amdgcn_mfma_f32_16x16x32_bf16(a0[m], b0[n], acc[m][n], 0, 0, 0);
        __builtin_amdgcn_s_setprio(0);
        __builtin_amdgcn_s_barrier();

        // ---- phase 1: read aF[4..7]; stage B(t+3); MFMA mh1; counted vmcnt ----
        bf16x8 a1[4];
#pragma unroll
        for (int m = 0; m < 4; m++)
            a1[m] = *reinterpret_cast<const bf16x8*>(tA + offA[4 + m]);
        GLL16(sB0 + sk, nB + dA0);
        GLL16(sB1 + sk, nB + dA1);
        __builtin_amdgcn_s_barrier();
        __builtin_amdgcn_s_setprio(1);
#pragma unroll
        for (int m = 0; m < 4; m++)
#pragma unroll
            for (int n = 0; n < 4; n++)
                acc[4 + m][n] = __builtin_amdgcn_mfma_f32_16x16x32_bf16(a1[m], b0[n], acc[4 + m][n], 0, 0, 0);
        __builtin_amdgcn_s_setprio(0);
        asm volatile("s_waitcnt vmcnt(8)" ::: "memory");   // tile t+1 landed; t+2,t+3 in flight
        __builtin_amdgcn_sched_barrier(0);
        __builtin_amdgcn_s_barrier();
    }
    asm volatile("s_waitcnt vmcnt(0)" ::: "memory");   // drain trailing stages
    __builtin_amdgcn_sched_barrier(0);

    // ---- epilogue: C/D frag col = lane&15, row = (lane>>4)*4 + j ----
    const int rBase = by * 256 + wr * 128 + fc * 4;
    const int cBase = bx * 256 + wc * 64 + fr;
    if (OUT_BF16) {
        unsigned short* C = (unsigned short*)Cp + (size_t)blockIdx.z * cBatch;
#pragma unroll
        for (int n = 0; n < 4; n++) {
            const int col = cBase + n * 16;
            const float bv = HAS_BIAS ? bias[col] : 0.0f;
#pragma unroll
            for (int m = 0; m < 8; m++) {
                const int row = rBase + m * 16;
#pragma unroll
                for (int j = 0; j < 4; j++)
                    C[(size_t)(row + j) * ldc + col] = f2bf(acc[m][n][j] + bv);
            }
        }
    } else {
        float* C = (float*)Cp + (size_t)blockIdx.z * cBatch;
#pragma unroll
        for (int n = 0; n < 4; n++) {
            const int col = cBase + n * 16;
#pragma unroll
            for (int m = 0; m < 8; m++) {
                const int row = rBase + m * 16;
#pragma unroll
                for (int j = 0; j < 4; j++)
                    C[(size_t)(row + j) * ldc + col] = acc[m][n][j];
            }
        }
    }
}

// ---------------------------------------------------------------------------
// Launch
// ---------------------------------------------------------------------------
extern "C" void kernel_launch(void* const* d_in, const int* in_sizes, int n_in,
                              void* d_out, int out_size, void* d_ws, size_t ws_size,
                              hipStream_t stream)
{
    const float* lstm = (const float*)d_in[0];   // [B,S,H] f32
    const float* W    = (const float*)d_in[1];   // [H,H]   f32
    const float* bias = (const float*)d_in[2];   // [H]     f32
    float* out = (float*)d_out;                  // [B,S,H] f32

    // workspace (ushorts): lstm_bf 16M | out_bf 16M | lstmT 16M | W_bf 1M | score_bf 32M
    unsigned short* lstm_bf = (unsigned short*)d_ws;
    unsigned short* out_bf  = lstm_bf + (size_t)BB * SS * HH;
    unsigned short* lstmT   = out_bf + (size_t)BB * SS * HH;
    unsigned short* W_bf    = lstmT + (size_t)BB * HH * SS;
    unsigned short* score   = W_bf + (size_t)HH * HH;

    // 1) lstm -> bf16 (row-major + transposed)
    transpose_cast<<<dim3(HH / 32, SS / 32, BB), dim3(256), 0, stream>>>(
        lstm, lstm_bf, lstmT);

    // 2) W -> bf16
    cast_f32_bf16<<<dim3(512), dim3(256), 0, stream>>>(W, W_bf, HH * HH / 4);

    // 3) out = lstm @ W^T + b   (M=16384, N=1024, K=1024), bf16 out
    gemm_nt_256<1, 1><<<dim3(256, 1, 1), dim3(512), 0, stream>>>(
        lstm_bf, 0, HH, W_bf, 0, HH, out_bf, 0, HH, bias, HH, HH / 256);

    // 4) score[b] = out[b] @ out[b]^T  (M=N=2048, K=1024), bf16 logits
    gemm_nt_256<1, 0><<<dim3(64, 1, BB), dim3(512), 0, stream>>>(
        out_bf, (long long)SS * HH, HH,
        out_bf, (long long)SS * HH, HH,
        score, (long long)SS * SS, SS, nullptr, HH, SS / 256);

    // 5) softmax rows, in-place bf16
    softmax_rows_bf16<<<dim3(BB * SS), dim3(256), 0, stream>>>(score);

    // 6) context[b] = attn[b] @ lstm[b] = attn[b] @ (lstmT[b])^T
    //    (M=2048, N=1024, K=2048), fp32 out
    gemm_nt_256<0, 0><<<dim3(32, 1, BB), dim3(512), 0, stream>>>(
        score, (long long)SS * SS, SS,
        lstmT, (long long)HH * SS, SS,
        out, (long long)SS * HH, HH, nullptr, SS, HH / 256);
}